// Round 12
// baseline (58.195 us; speedup 1.0000x reference)
//
#include <hip/hip_runtime.h>
#include <hip/hip_bf16.h>
#include <cstdint>

#define NROWS 262144
#define DIM 128

typedef float f32x4 __attribute__((ext_vector_type(4)));
typedef short s16x8 __attribute__((ext_vector_type(8)));
typedef unsigned short u16x8 __attribute__((ext_vector_type(8)));
typedef unsigned int u32x4 __attribute__((ext_vector_type(4)));

__device__ __forceinline__ unsigned short cvbf(float f){
  unsigned u = __float_as_uint(f);
  return (unsigned short)((u + 0x8000u) >> 16);
}

__device__ __forceinline__ void ldsload16(const void* gp, void* lp){
  __builtin_amdgcn_global_load_lds((const __attribute__((address_space(1))) void*)gp,
                                   (__attribute__((address_space(3))) void*)lp,
                                   16, 0, 0);
}

// ---------------- prep kernel: weight repack + dtype detect into d_ws ----------------
// ws[0..65536): W1T bf16, row n=g*64+h (256 x 256B), byte = n*256 + (k*2 ^ ((n&7)<<4))
// ws[65536..73728): W2T bf16, row t=g*16+p (64 x 128B); element slot e (=ks*32+q*8+j)
//   holds W2[g][h(e)][p], h(e) = (e&32)|((e&4)<<2)|((e>>1)&12)|(e&3)  (k-slot permutation
//   matching GEMM1's C^T fragment layout -> GEMM2 needs no hidden transpose), p>=4 zeros.
// ws[73728]: gshift (0=int32 gids, 1=int64) ; ws[73732]: mshift (0=byte mask, 2=int32 mask)
__global__ void prep_kernel(const float* __restrict__ W1, const float* __restrict__ W2,
                            const void* __restrict__ gids_raw, const void* __restrict__ mask_raw,
                            unsigned char* __restrict__ ws){
  int tid = threadIdx.x, bid = blockIdx.x;
  if (bid < 16){
    int chunk = bid*256 + tid;
    int n    = chunk >> 4;
    int kb16 = chunk & 15;
    int d0   = kb16 * 8;
    int g = n >> 6, h = n & 63;
    u16x8 v;
#pragma unroll
    for (int j=0;j<8;++j) v[j] = cvbf(W1[((g*DIM) + d0 + j)*64 + h]);
    unsigned off = (unsigned)n*256 + (((unsigned)kb16*16) ^ (((unsigned)(n&7))<<4));
    *(u16x8*)(ws + off) = v;
  } else {
#pragma unroll
    for (int i=0;i<16;++i){
      int el = tid + i*256;          // 0..4095 elements of W2T
      int t  = el >> 6;              // row t = g*16+p
      int e  = el & 63;              // k-slot within row
      int g = t >> 4, p = t & 15;
      int h = (e & 32) | ((e & 4) << 2) | ((e >> 1) & 12) | (e & 3);
      float f = (p < 4) ? W2[(g*64 + h)*4 + p] : 0.0f;
      unsigned off = 65536u + (unsigned)t*128 + (((unsigned)(e*2)) ^ (((unsigned)(t&7))<<4));
      *(unsigned short*)(ws + off) = cvbf(f);
    }
    if (tid < 64){
      const int* g32 = (const int*)gids_raw;
      int accg = 0;
#pragma unroll
      for (int i=0;i<8;++i) accg |= g32[(tid*8 + i)*2 + 1];
      const unsigned char* m8 = (const unsigned char*)mask_raw;
      int accm = 0;
#pragma unroll
      for (int i=0;i<16;++i){
        int off = tid*16 + i;
        if (off & 3) accm |= m8[off];
      }
      unsigned long long bg = __ballot(accg != 0);
      unsigned long long bm = __ballot(accm != 0);
      if (tid == 0){
        *(int*)(ws + 73728) = (bg == 0ull) ? 1 : 0;
        *(int*)(ws + 73732) = (bm == 0ull) ? 2 : 0;
      }
    }
  }
}

// ---------------- main kernel: 512-thread blocks (8 waves), 2 blocks/CU, nt=2 units ----------------
#define LDS_W2T 65536
#define LDS_B1  (65536+8192)
#define LDS_TOTAL (65536+8192+1024)

__global__ __launch_bounds__(512, 4)
void actor_kernel(const float* __restrict__ X, const int* __restrict__ gids,
                  const unsigned char* __restrict__ fmask,
                  const float* __restrict__ b1, const float* __restrict__ b2,
                  const unsigned char* __restrict__ ws, float* __restrict__ out){
  __shared__ char smem[LDS_TOTAL];
  const int tid  = threadIdx.x;
  const int wave = tid >> 6, lane = tid & 63;
  const int q    = lane >> 4, rS = lane & 15;
  const int swzA = (rS & 7) << 4;

  const int gshift = *(const int*)(ws + 73728);
  const int mshift = *(const int*)(ws + 73732);

  // --- stage W1T + W2T + b1 to LDS once per block (8 waves cooperate) ---
#pragma unroll
  for (int i=0;i<8;++i){
    int off = i*8192 + wave*1024;
    ldsload16(ws + off + lane*16, smem + off);
  }
  {
    int off = wave*1024;
    ldsload16(ws + 65536 + off + lane*16, smem + LDS_W2T + off);
  }
  if (wave == 0)
    ldsload16((const unsigned char*)b1 + lane*16, smem + LDS_B1);
  __syncthreads();   // weights resident

  const long base = (long)blockIdx.x * 512 + wave * 64;
  const f32x4 z = (f32x4){0.f,0.f,0.f,0.f};

#pragma unroll 1
  for (int u=0; u<2; ++u){
    const long row0 = base + u*32 + rS;   // nt=0 row; nt=1 is +16

    // --- loads for both 16-row halves ---
    int gb0, gb1;
    u32x4 mb0, mb1;
    f32x4 xb[2][4][2];
    {
      gb0 = gids[(size_t)row0 << gshift];
      gb1 = gids[(size_t)(row0 + 16) << gshift];
      if (mshift){
        mb0 = *(const u32x4*)(fmask + row0*16);
        mb1 = *(const u32x4*)(fmask + (row0+16)*16);
      } else {
        unsigned w0 = *(const unsigned*)(fmask + row0*4);
        unsigned w1 = *(const unsigned*)(fmask + (row0+16)*4);
        mb0[0]=w0&0xffu; mb0[1]=(w0>>8)&0xffu; mb0[2]=(w0>>16)&0xffu; mb0[3]=w0>>24;
        mb1[0]=w1&0xffu; mb1[1]=(w1>>8)&0xffu; mb1[2]=(w1>>16)&0xffu; mb1[3]=w1>>24;
      }
      const float* xp0 = X + row0 * DIM + q*8;
      const float* xp1 = X + (row0 + 16) * DIM + q*8;
#pragma unroll
      for (int k=0;k<4;++k){
        xb[0][k][0] = *(const f32x4*)(xp0 + k*32);
        xb[0][k][1] = *(const f32x4*)(xp0 + k*32 + 4);
        xb[1][k][0] = *(const f32x4*)(xp1 + k*32);
        xb[1][k][1] = *(const f32x4*)(xp1 + k*32 + 4);
      }
    }
    __builtin_amdgcn_sched_barrier(0);

    // --- convert to bf16 B-fragments (xb dies here) ---
    s16x8 bfr[2][4];
#pragma unroll
    for (int nt=0;nt<2;++nt)
#pragma unroll
      for (int k=0;k<4;++k){
        s16x8 v;
#pragma unroll
        for (int j=0;j<4;++j){ v[j] = (short)cvbf(xb[nt][k][0][j]); v[j+4] = (short)cvbf(xb[nt][k][1][j]); }
        bfr[nt][k] = v;
      }
    __builtin_amdgcn_sched_barrier(0);

    // --- fused GEMM1 -> +b1/relu -> GEMM2, per mt-pair; each LDS read feeds 2 MFMAs ---
    f32x4 acc2[4][2];
#pragma unroll
    for (int p=0;p<8;++p){
      f32x4 aA0, aA1, aB0, aB1;
#pragma unroll
      for (int k=0;k<4;++k){
        const s16x8 sA = *(const s16x8*)(smem + ((2*p  )*16 + rS)*256 + ((k*64 + q*16) ^ swzA));
        const s16x8 sB = *(const s16x8*)(smem + ((2*p+1)*16 + rS)*256 + ((k*64 + q*16) ^ swzA));
        aA0 = __builtin_amdgcn_mfma_f32_16x16x32_bf16(sA, bfr[0][k], (k==0)? z : aA0, 0,0,0);
        aA1 = __builtin_amdgcn_mfma_f32_16x16x32_bf16(sA, bfr[1][k], (k==0)? z : aA1, 0,0,0);
        aB0 = __builtin_amdgcn_mfma_f32_16x16x32_bf16(sB, bfr[0][k], (k==0)? z : aB0, 0,0,0);
        aB1 = __builtin_amdgcn_mfma_f32_16x16x32_bf16(sB, bfr[1][k], (k==0)? z : aB1, 0,0,0);
      }
      const f32x4 b1A = *(const f32x4*)(smem + LDS_B1 + (2*p  )*64 + q*16);
      const f32x4 b1B = *(const f32x4*)(smem + LDS_B1 + (2*p+1)*64 + q*16);
      const s16x8 af = *(const s16x8*)(smem + LDS_W2T + ((p>>1)*16 + rS)*128
                                       + (((p&1)*64 + q*16) ^ swzA));
      // nt = 0
      {
        f32x4 vA = aA0 + b1A;
        f32x4 vB = aB0 + b1B;
#pragma unroll
        for (int j=0;j<4;++j){
          vA[j] = vA[j] > 0.f ? vA[j] : 0.f;
          vB[j] = vB[j] > 0.f ? vB[j] : 0.f;
        }
        s16x8 hf;
#pragma unroll
        for (int j=0;j<4;++j){ hf[j] = (short)cvbf(vA[j]); hf[j+4] = (short)cvbf(vB[j]); }
        acc2[p>>1][0] = __builtin_amdgcn_mfma_f32_16x16x32_bf16(
            af, hf, (p&1) ? acc2[p>>1][0] : z, 0,0,0);
      }
      // nt = 1
      {
        f32x4 vA = aA1 + b1A;
        f32x4 vB = aB1 + b1B;
#pragma unroll
        for (int j=0;j<4;++j){
          vA[j] = vA[j] > 0.f ? vA[j] : 0.f;
          vB[j] = vB[j] > 0.f ? vB[j] : 0.f;
        }
        s16x8 hf;
#pragma unroll
        for (int j=0;j<4;++j){ hf[j] = (short)cvbf(vA[j]); hf[j+4] = (short)cvbf(vB[j]); }
        acc2[p>>1][1] = __builtin_amdgcn_mfma_f32_16x16x32_bf16(
            af, hf, (p&1) ? acc2[p>>1][1] : z, 0,0,0);
      }
      __builtin_amdgcn_sched_barrier(0);
    }

    // --- epilogue nt=0 ---
    {
      int g = gb0;
      f32x4 lv = acc2[0][0];
      lv = (g==1) ? acc2[1][0] : lv;
      lv = (g==2) ? acc2[2][0] : lv;
      lv = (g==3) ? acc2[3][0] : lv;
      const f32x4 bs = *(const f32x4*)(b2 + g*4);
      f32x4 li;
#pragma unroll
      for (int p=0;p<4;++p)
        li[p] = mb0[p] ? (lv[p] + bs[p]) : -1e9f;
      float m = fmaxf(fmaxf(li[0],li[1]), fmaxf(li[2],li[3]));
      f32x4 e;
#pragma unroll
      for (int p=0;p<4;++p) e[p] = __expf(li[p] - m);
      float inv = 1.0f / (e[0]+e[1]+e[2]+e[3]);
      f32x4 o;
#pragma unroll
      for (int p=0;p<4;++p) o[p] = e[p] * inv;
      if (q == 0)
        *(f32x4*)(out + row0*4) = o;
    }
    // --- epilogue nt=1 ---
    {
      int g = gb1;
      f32x4 lv = acc2[0][1];
      lv = (g==1) ? acc2[1][1] : lv;
      lv = (g==2) ? acc2[2][1] : lv;
      lv = (g==3) ? acc2[3][1] : lv;
      const f32x4 bs = *(const f32x4*)(b2 + g*4);
      f32x4 li;
#pragma unroll
      for (int p=0;p<4;++p)
        li[p] = mb1[p] ? (lv[p] + bs[p]) : -1e9f;
      float m = fmaxf(fmaxf(li[0],li[1]), fmaxf(li[2],li[3]));
      f32x4 e;
#pragma unroll
      for (int p=0;p<4;++p) e[p] = __expf(li[p] - m);
      float inv = 1.0f / (e[0]+e[1]+e[2]+e[3]);
      f32x4 o;
#pragma unroll
      for (int p=0;p<4;++p) o[p] = e[p] * inv;
      if (q == 0)
        *(f32x4*)(out + (row0+16)*4) = o;
    }
  }
}

extern "C" void kernel_launch(void* const* d_in, const int* in_sizes, int n_in,
                              void* d_out, int out_size, void* d_ws, size_t ws_size,
                              hipStream_t stream){
  const float* X  = (const float*)d_in[0];
  const void*  gi = d_in[1];
  const void*  fm = d_in[2];
  const float* W1 = (const float*)d_in[3];
  const float* b1 = (const float*)d_in[4];
  const float* W2 = (const float*)d_in[5];
  const float* b2 = (const float*)d_in[6];
  unsigned char* ws = (unsigned char*)d_ws;
  float* out = (float*)d_out;

  prep_kernel<<<dim3(17), dim3(256), 0, stream>>>(W1, W2, gi, fm, ws);
  actor_kernel<<<dim3(512), dim3(512), 0, stream>>>(X, (const int*)gi,
                                                    (const unsigned char*)fm,
                                                    b1, b2, ws, out);
}

// Round 13
// 52.930 us; speedup vs baseline: 1.0995x; 1.0995x over previous
//
#include <hip/hip_runtime.h>
#include <hip/hip_bf16.h>
#include <cstdint>

#define NROWS 262144
#define DIM 128
#define NMB  2052            // main sorted-path blocks (covers 262144 + padding)

// ---- ws layout (bytes) ----
#define WS_GSHIFT 73728
#define WS_MSHIFT 73732
#define CNTB_OFF  73792      // int cntb[512][4]
#define SEGS_OFF  81984      // int segs[5]
#define BSTART_OFF 82432     // int bstart[512][4]
#define PERM_OFF  90880      // int perm[NMB*128]
#define WS_NEEDED (PERM_OFF + NMB*128*4)

typedef float f32x4 __attribute__((ext_vector_type(4)));
typedef short s16x8 __attribute__((ext_vector_type(8)));
typedef unsigned short u16x8 __attribute__((ext_vector_type(8)));
typedef unsigned int u32x4 __attribute__((ext_vector_type(4)));

__device__ __forceinline__ unsigned short cvbf(float f){
  unsigned u = __float_as_uint(f);
  return (unsigned short)((u + 0x8000u) >> 16);
}

__device__ __forceinline__ void ldsload16(const void* gp, void* lp){
  __builtin_amdgcn_global_load_lds((const __attribute__((address_space(1))) void*)gp,
                                   (__attribute__((address_space(3))) void*)lp,
                                   16, 0, 0);
}

// ---------------- prep: weight repack + dtype detect (unchanged layout) ----------------
__global__ void prep_kernel(const float* __restrict__ W1, const float* __restrict__ W2,
                            const void* __restrict__ gids_raw, const void* __restrict__ mask_raw,
                            unsigned char* __restrict__ ws){
  int tid = threadIdx.x, bid = blockIdx.x;
  if (bid < 16){
    int chunk = bid*256 + tid;
    int n    = chunk >> 4;
    int kb16 = chunk & 15;
    int d0   = kb16 * 8;
    int g = n >> 6, h = n & 63;
    u16x8 v;
#pragma unroll
    for (int j=0;j<8;++j) v[j] = cvbf(W1[((g*DIM) + d0 + j)*64 + h]);
    unsigned off = (unsigned)n*256 + (((unsigned)kb16*16) ^ (((unsigned)(n&7))<<4));
    *(u16x8*)(ws + off) = v;
  } else {
#pragma unroll
    for (int i=0;i<16;++i){
      int el = tid + i*256;
      int t  = el >> 6;
      int e  = el & 63;
      int g = t >> 4, p = t & 15;
      int h = (e & 32) | ((e & 4) << 2) | ((e >> 1) & 12) | (e & 3);
      float f = (p < 4) ? W2[(g*64 + h)*4 + p] : 0.0f;
      unsigned off = 65536u + (unsigned)t*128 + (((unsigned)(e*2)) ^ (((unsigned)(t&7))<<4));
      *(unsigned short*)(ws + off) = cvbf(f);
    }
    if (tid < 64){
      const int* g32 = (const int*)gids_raw;
      int accg = 0;
#pragma unroll
      for (int i=0;i<8;++i) accg |= g32[(tid*8 + i)*2 + 1];
      const unsigned char* m8 = (const unsigned char*)mask_raw;
      int accm = 0;
#pragma unroll
      for (int i=0;i<16;++i){
        int off = tid*16 + i;
        if (off & 3) accm |= m8[off];
      }
      unsigned long long bg = __ballot(accg != 0);
      unsigned long long bm = __ballot(accm != 0);
      if (tid == 0){
        *(int*)(ws + WS_GSHIFT) = (bg == 0ull) ? 1 : 0;
        *(int*)(ws + WS_MSHIFT) = (bm == 0ull) ? 2 : 0;
      }
    }
  }
}

// ---------------- sort chain ----------------
__global__ void hist_kernel(const int* __restrict__ gids, unsigned char* __restrict__ ws){
  __shared__ int h[4];
  int tid = threadIdx.x, bid = blockIdx.x;
  if (tid < 4) h[tid] = 0;
  __syncthreads();
  const int gshift = *(const int*)(ws + WS_GSHIFT);
#pragma unroll
  for (int i=0;i<2;++i){
    int row = bid*512 + tid + i*256;
    int g = gids[(size_t)row << gshift] & 3;
    atomicAdd(&h[g], 1);
  }
  __syncthreads();
  if (tid < 4) ((int*)(ws + CNTB_OFF))[bid*4 + tid] = h[tid];
}

__global__ void seg_kernel(unsigned char* __restrict__ ws){
  __shared__ int A[4][512], B[4][512];
  __shared__ int segL[5], totL[4];
  int tid = threadIdx.x;
  const int* cntb = (const int*)(ws + CNTB_OFF);
  for (int e = tid; e < 2048; e += 256){
    int g = e >> 9, i = e & 511;
    A[g][i] = cntb[i*4 + g];
  }
  __syncthreads();
  bool ab = true;   // true: src=A dst=B
  for (int off = 1; off < 512; off <<= 1){
    for (int e = tid; e < 2048; e += 256){
      int g = e >> 9, i = e & 511;
      int v = ab ? A[g][i] : B[g][i];
      if (i >= off) v += ab ? A[g][i-off] : B[g][i-off];
      if (ab) B[g][i] = v; else A[g][i] = v;
    }
    __syncthreads();
    ab = !ab;
  }
  // final inclusive scan is in (ab ? A : B)
  if (tid == 0){
    int s = 0;
    for (int g=0; g<4; ++g){
      int tot = ab ? A[g][511] : B[g][511];
      totL[g] = tot;
      segL[g] = s;
      s += ((tot + 127) >> 7) << 7;
    }
    segL[4] = s;
    int* segs = (int*)(ws + SEGS_OFF);
    for (int g=0; g<5; ++g) segs[g] = segL[g];
  }
  __syncthreads();
  int* bstart = (int*)(ws + BSTART_OFF);
  for (int e = tid; e < 2048; e += 256){
    int g = e >> 9, i = e & 511;
    int incl = ab ? A[g][i] : B[g][i];
    bstart[i*4 + g] = segL[g] + incl - cntb[i*4 + g];
  }
  int* perm = (int*)(ws + PERM_OFF);
  for (int g=0; g<4; ++g){
    int beg = segL[g] + totL[g];
    int end = (g < 3) ? segL[g+1] : segL[4];
    for (int i = beg + tid; i < end; i += 256) perm[i] = -1;
  }
  for (int i = segL[4] + tid; i < NMB*128; i += 256) perm[i] = -1;
}

__global__ void scat_kernel(const int* __restrict__ gids, unsigned char* __restrict__ ws){
  __shared__ int cur[4];
  int tid = threadIdx.x, bid = blockIdx.x;
  const int gshift = *(const int*)(ws + WS_GSHIFT);
  if (tid < 4) cur[tid] = ((const int*)(ws + BSTART_OFF))[bid*4 + tid];
  __syncthreads();
  int* perm = (int*)(ws + PERM_OFF);
#pragma unroll
  for (int i=0;i<2;++i){
    int row = bid*512 + tid + i*256;
    int g = gids[(size_t)row << gshift] & 3;
    int pos = atomicAdd(&cur[g], 1);
    perm[pos] = row;
  }
}

// ---------------- sorted main kernel: one group per block, 18.7KB LDS ----------------
#define W2G_OFF 16384
#define B1G_OFF (16384+2048)
#define LDS_S_TOTAL (16384+2048+256)

__global__ __launch_bounds__(256, 2)
void actor_sorted(const float* __restrict__ X,
                  const unsigned char* __restrict__ fmask,
                  const float* __restrict__ b1, const float* __restrict__ b2,
                  const unsigned char* __restrict__ ws, float* __restrict__ out){
  __shared__ char smem[LDS_S_TOTAL];
  const int tid  = threadIdx.x;
  const int wave = tid >> 6, lane = tid & 63;
  const int q    = lane >> 4, rS = lane & 15;
  const int swzA = (rS & 7) << 4;

  const int mshift = *(const int*)(ws + WS_MSHIFT);
  const int* segs = (const int*)(ws + SEGS_OFF);
  const int p0 = blockIdx.x * 128;
  const int g = (p0 >= segs[1]) + (p0 >= segs[2]) + (p0 >= segs[3]);

  // --- stage group-g weights ---
#pragma unroll
  for (int i=0;i<4;++i){
    int off = i*4096 + wave*1024;
    ldsload16(ws + g*16384 + off + lane*16, smem + off);
  }
  if (wave < 2)
    ldsload16(ws + 65536 + g*2048 + wave*1024 + lane*16, smem + W2G_OFF + wave*1024 + lane*16);
  if (wave == 2 && lane < 16)
    ldsload16((const unsigned char*)b1 + g*256 + lane*16, smem + B1G_OFF + lane*16);
  __syncthreads();

  const f32x4 z = (f32x4){0.f,0.f,0.f,0.f};
  const int pos = p0 + wave*32;
  const int* perm = (const int*)(ws + PERM_OFF);
  const int r0 = perm[pos + rS];
  const int r1 = perm[pos + 16 + rS];
  const int v0 = (r0 >= 0), v1 = (r1 >= 0);
  const long rr0 = v0 ? r0 : 0, rr1 = v1 ? r1 : 0;

  // --- masks ---
  u32x4 mb0, mb1;
  if (mshift){
    mb0 = *(const u32x4*)(fmask + rr0*16);
    mb1 = *(const u32x4*)(fmask + rr1*16);
  } else {
    unsigned w0 = *(const unsigned*)(fmask + rr0*4);
    unsigned w1 = *(const unsigned*)(fmask + rr1*4);
    mb0[0]=w0&0xffu; mb0[1]=(w0>>8)&0xffu; mb0[2]=(w0>>16)&0xffu; mb0[3]=w0>>24;
    mb1[0]=w1&0xffu; mb1[1]=(w1>>8)&0xffu; mb1[2]=(w1>>16)&0xffu; mb1[3]=w1>>24;
  }

  // --- X loads (gather, 512B-contiguous per row) ---
  f32x4 xb[2][4][2];
  {
    const float* xp0 = X + rr0 * DIM + q*8;
    const float* xp1 = X + rr1 * DIM + q*8;
#pragma unroll
    for (int k=0;k<4;++k){
      xb[0][k][0] = *(const f32x4*)(xp0 + k*32);
      xb[0][k][1] = *(const f32x4*)(xp0 + k*32 + 4);
      xb[1][k][0] = *(const f32x4*)(xp1 + k*32);
      xb[1][k][1] = *(const f32x4*)(xp1 + k*32 + 4);
    }
  }
  __builtin_amdgcn_sched_barrier(0);

  // --- cvt ---
  s16x8 bfr[2][4];
#pragma unroll
  for (int nt=0;nt<2;++nt)
#pragma unroll
    for (int k=0;k<4;++k){
      s16x8 v;
#pragma unroll
      for (int j=0;j<4;++j){ v[j] = (short)cvbf(xb[nt][k][0][j]); v[j+4] = (short)cvbf(xb[nt][k][1][j]); }
      bfr[nt][k] = v;
    }
  __builtin_amdgcn_sched_barrier(0);

  // --- fused GEMM1(own group, 64 cols) -> +b1/relu -> GEMM2, pinned ---
  f32x4 acc2[2];
#pragma unroll
  for (int p=0;p<2;++p){
    f32x4 aA0, aA1, aB0, aB1;
#pragma unroll
    for (int k=0;k<4;++k){
      const s16x8 sA = *(const s16x8*)(smem + ((2*p  )*16 + rS)*256 + ((k*64 + q*16) ^ swzA));
      const s16x8 sB = *(const s16x8*)(smem + ((2*p+1)*16 + rS)*256 + ((k*64 + q*16) ^ swzA));
      aA0 = __builtin_amdgcn_mfma_f32_16x16x32_bf16(sA, bfr[0][k], (k==0)? z : aA0, 0,0,0);
      aA1 = __builtin_amdgcn_mfma_f32_16x16x32_bf16(sA, bfr[1][k], (k==0)? z : aA1, 0,0,0);
      aB0 = __builtin_amdgcn_mfma_f32_16x16x32_bf16(sB, bfr[0][k], (k==0)? z : aB0, 0,0,0);
      aB1 = __builtin_amdgcn_mfma_f32_16x16x32_bf16(sB, bfr[1][k], (k==0)? z : aB1, 0,0,0);
    }
    const f32x4 b1A = *(const f32x4*)(smem + B1G_OFF + (2*p  )*64 + q*16);
    const f32x4 b1B = *(const f32x4*)(smem + B1G_OFF + (2*p+1)*64 + q*16);
    const s16x8 af = *(const s16x8*)(smem + W2G_OFF + rS*128 + ((p*64 + q*16) ^ swzA));
    {
      f32x4 vA = aA0 + b1A, vB = aB0 + b1B;
#pragma unroll
      for (int j=0;j<4;++j){ vA[j] = vA[j] > 0.f ? vA[j] : 0.f; vB[j] = vB[j] > 0.f ? vB[j] : 0.f; }
      s16x8 hf;
#pragma unroll
      for (int j=0;j<4;++j){ hf[j] = (short)cvbf(vA[j]); hf[j+4] = (short)cvbf(vB[j]); }
      acc2[0] = __builtin_amdgcn_mfma_f32_16x16x32_bf16(af, hf, p ? acc2[0] : z, 0,0,0);
    }
    {
      f32x4 vA = aA1 + b1A, vB = aB1 + b1B;
#pragma unroll
      for (int j=0;j<4;++j){ vA[j] = vA[j] > 0.f ? vA[j] : 0.f; vB[j] = vB[j] > 0.f ? vB[j] : 0.f; }
      s16x8 hf;
#pragma unroll
      for (int j=0;j<4;++j){ hf[j] = (short)cvbf(vA[j]); hf[j+4] = (short)cvbf(vB[j]); }
      acc2[1] = __builtin_amdgcn_mfma_f32_16x16x32_bf16(af, hf, p ? acc2[1] : z, 0,0,0);
    }
    __builtin_amdgcn_sched_barrier(0);
  }

  // --- epilogues (group uniform: no select chain) ---
  const f32x4 bs = *(const f32x4*)(b2 + g*4);
#pragma unroll
  for (int nt=0;nt<2;++nt){
    u32x4 mb = nt ? mb1 : mb0;
    f32x4 lv = acc2[nt];
    f32x4 li;
#pragma unroll
    for (int p=0;p<4;++p)
      li[p] = mb[p] ? (lv[p] + bs[p]) : -1e9f;
    float m = fmaxf(fmaxf(li[0],li[1]), fmaxf(li[2],li[3]));
    f32x4 e;
#pragma unroll
    for (int p=0;p<4;++p) e[p] = __expf(li[p] - m);
    float inv = 1.0f / (e[0]+e[1]+e[2]+e[3]);
    f32x4 o;
#pragma unroll
    for (int p=0;p<4;++p) o[p] = e[p] * inv;
    int valid = nt ? v1 : v0;
    long r = nt ? rr1 : rr0;
    if (q == 0 && valid)
      *(f32x4*)(out + r*4) = o;
  }
}

// ---------------- dense fallback (round-9 kernel, known-good 37.7us) ----------------
#define LDS_W2T 65536
#define LDS_B1  (65536+8192)
#define LDS_TOTAL (65536+8192+1024)

__global__ __launch_bounds__(256, 2)
void actor_dense(const float* __restrict__ X, const int* __restrict__ gids,
                 const unsigned char* __restrict__ fmask,
                 const float* __restrict__ b1, const float* __restrict__ b2,
                 const unsigned char* __restrict__ ws, float* __restrict__ out){
  __shared__ char smem[LDS_TOTAL];
  const int tid  = threadIdx.x;
  const int wave = tid >> 6, lane = tid & 63;
  const int q    = lane >> 4, rS = lane & 15;
  const int swzA = (rS & 7) << 4;

  const int gshift = *(const int*)(ws + WS_GSHIFT);
  const int mshift = *(const int*)(ws + WS_MSHIFT);

#pragma unroll
  for (int i=0;i<16;++i){
    int off = i*4096 + wave*1024;
    ldsload16(ws + off + lane*16, smem + off);
  }
#pragma unroll
  for (int i=0;i<2;++i){
    int off = i*4096 + wave*1024;
    ldsload16(ws + 65536 + off + lane*16, smem + LDS_W2T + off);
  }
  if (wave == 0)
    ldsload16((const unsigned char*)b1 + lane*16, smem + LDS_B1);
  __syncthreads();

  const long base = (long)blockIdx.x * 512 + wave * 128;
  const f32x4 z = (f32x4){0.f,0.f,0.f,0.f};

#pragma unroll 1
  for (int u=0; u<4; ++u){
    const long row0 = base + u*32 + rS;
    int gb0, gb1;
    u32x4 mb0, mb1;
    f32x4 xb[2][4][2];
    {
      gb0 = gids[(size_t)row0 << gshift];
      gb1 = gids[(size_t)(row0 + 16) << gshift];
      if (mshift){
        mb0 = *(const u32x4*)(fmask + row0*16);
        mb1 = *(const u32x4*)(fmask + (row0+16)*16);
      } else {
        unsigned w0 = *(const unsigned*)(fmask + row0*4);
        unsigned w1 = *(const unsigned*)(fmask + (row0+16)*4);
        mb0[0]=w0&0xffu; mb0[1]=(w0>>8)&0xffu; mb0[2]=(w0>>16)&0xffu; mb0[3]=w0>>24;
        mb1[0]=w1&0xffu; mb1[1]=(w1>>8)&0xffu; mb1[2]=(w1>>16)&0xffu; mb1[3]=w1>>24;
      }
      const float* xp0 = X + row0 * DIM + q*8;
      const float* xp1 = X + (row0 + 16) * DIM + q*8;
#pragma unroll
      for (int k=0;k<4;++k){
        xb[0][k][0] = *(const f32x4*)(xp0 + k*32);
        xb[0][k][1] = *(const f32x4*)(xp0 + k*32 + 4);
        xb[1][k][0] = *(const f32x4*)(xp1 + k*32);
        xb[1][k][1] = *(const f32x4*)(xp1 + k*32 + 4);
      }
    }
    __builtin_amdgcn_sched_barrier(0);

    s16x8 bfr[2][4];
#pragma unroll
    for (int nt=0;nt<2;++nt)
#pragma unroll
      for (int k=0;k<4;++k){
        s16x8 v;
#pragma unroll
        for (int j=0;j<4;++j){ v[j] = (short)cvbf(xb[nt][k][0][j]); v[j+4] = (short)cvbf(xb[nt][k][1][j]); }
        bfr[nt][k] = v;
      }
    __builtin_amdgcn_sched_barrier(0);

    f32x4 acc2[4][2];
#pragma unroll
    for (int p=0;p<8;++p){
      f32x4 aA0, aA1, aB0, aB1;
#pragma unroll
      for (int k=0;k<4;++k){
        const s16x8 sA = *(const s16x8*)(smem + ((2*p  )*16 + rS)*256 + ((k*64 + q*16) ^ swzA));
        const s16x8 sB = *(const s16x8*)(smem + ((2*p+1)*16 + rS)*256 + ((k*64 + q*16) ^ swzA));
        aA0 = __builtin_amdgcn_mfma_f32_16x16x32_bf16(sA, bfr[0][k], (k==0)? z : aA0, 0,0,0);
        aA1 = __builtin_amdgcn_mfma_f32_16x16x32_bf16(sA, bfr[1][k], (k==0)? z : aA1, 0,0,0);
        aB0 = __builtin_amdgcn_mfma_f32_16x16x32_bf16(sB, bfr[0][k], (k==0)? z : aB0, 0,0,0);
        aB1 = __builtin_amdgcn_mfma_f32_16x16x32_bf16(sB, bfr[1][k], (k==0)? z : aB1, 0,0,0);
      }
      const f32x4 b1A = *(const f32x4*)(smem + LDS_B1 + (2*p  )*64 + q*16);
      const f32x4 b1B = *(const f32x4*)(smem + LDS_B1 + (2*p+1)*64 + q*16);
      const s16x8 af = *(const s16x8*)(smem + LDS_W2T + ((p>>1)*16 + rS)*128
                                       + (((p&1)*64 + q*16) ^ swzA));
      {
        f32x4 vA = aA0 + b1A, vB = aB0 + b1B;
#pragma unroll
        for (int j=0;j<4;++j){ vA[j] = vA[j] > 0.f ? vA[j] : 0.f; vB[j] = vB[j] > 0.f ? vB[j] : 0.f; }
        s16x8 hf;
#pragma unroll
        for (int j=0;j<4;++j){ hf[j] = (short)cvbf(vA[j]); hf[j+4] = (short)cvbf(vB[j]); }
        acc2[p>>1][0] = __builtin_amdgcn_mfma_f32_16x16x32_bf16(af, hf, (p&1) ? acc2[p>>1][0] : z, 0,0,0);
      }
      {
        f32x4 vA = aA1 + b1A, vB = aB1 + b1B;
#pragma unroll
        for (int j=0;j<4;++j){ vA[j] = vA[j] > 0.f ? vA[j] : 0.f; vB[j] = vB[j] > 0.f ? vB[j] : 0.f; }
        s16x8 hf;
#pragma unroll
        for (int j=0;j<4;++j){ hf[j] = (short)cvbf(vA[j]); hf[j+4] = (short)cvbf(vB[j]); }
        acc2[p>>1][1] = __builtin_amdgcn_mfma_f32_16x16x32_bf16(af, hf, (p&1) ? acc2[p>>1][1] : z, 0,0,0);
      }
      __builtin_amdgcn_sched_barrier(0);
    }

#pragma unroll
    for (int nt=0;nt<2;++nt){
      int g = nt ? gb1 : gb0;
      u32x4 mb = nt ? mb1 : mb0;
      f32x4 lv = acc2[0][nt];
      lv = (g==1) ? acc2[1][nt] : lv;
      lv = (g==2) ? acc2[2][nt] : lv;
      lv = (g==3) ? acc2[3][nt] : lv;
      const f32x4 bs = *(const f32x4*)(b2 + g*4);
      f32x4 li;
#pragma unroll
      for (int p=0;p<4;++p)
        li[p] = mb[p] ? (lv[p] + bs[p]) : -1e9f;
      float m = fmaxf(fmaxf(li[0],li[1]), fmaxf(li[2],li[3]));
      f32x4 e;
#pragma unroll
      for (int p=0;p<4;++p) e[p] = __expf(li[p] - m);
      float inv = 1.0f / (e[0]+e[1]+e[2]+e[3]);
      f32x4 o;
#pragma unroll
      for (int p=0;p<4;++p) o[p] = e[p] * inv;
      if (q == 0)
        *(f32x4*)(out + (row0 + nt*16)*4) = o;
    }
  }
}

extern "C" void kernel_launch(void* const* d_in, const int* in_sizes, int n_in,
                              void* d_out, int out_size, void* d_ws, size_t ws_size,
                              hipStream_t stream){
  const float* X  = (const float*)d_in[0];
  const void*  gi = d_in[1];
  const void*  fm = d_in[2];
  const float* W1 = (const float*)d_in[3];
  const float* b1 = (const float*)d_in[4];
  const float* W2 = (const float*)d_in[5];
  const float* b2 = (const float*)d_in[6];
  unsigned char* ws = (unsigned char*)d_ws;
  float* out = (float*)d_out;

  prep_kernel<<<dim3(17), dim3(256), 0, stream>>>(W1, W2, gi, fm, ws);

  if (ws_size >= (size_t)WS_NEEDED){
    hist_kernel<<<dim3(512), dim3(256), 0, stream>>>((const int*)gi, ws);
    seg_kernel <<<dim3(1),   dim3(256), 0, stream>>>(ws);
    scat_kernel<<<dim3(512), dim3(256), 0, stream>>>((const int*)gi, ws);
    actor_sorted<<<dim3(NMB), dim3(256), 0, stream>>>(X, (const unsigned char*)fm,
                                                      b1, b2, ws, out);
  } else {
    actor_dense<<<dim3(512), dim3(256), 0, stream>>>(X, (const int*)gi,
                                                     (const unsigned char*)fm,
                                                     b1, b2, ws, out);
  }
}

// Round 14
// 47.735 us; speedup vs baseline: 1.2191x; 1.1088x over previous
//
#include <hip/hip_runtime.h>
#include <hip/hip_bf16.h>
#include <cstdint>

#define NROWS 262144
#define DIM 128

typedef float f32x4 __attribute__((ext_vector_type(4)));
typedef short s16x8 __attribute__((ext_vector_type(8)));
typedef unsigned short u16x8 __attribute__((ext_vector_type(8)));
typedef unsigned int u32x4 __attribute__((ext_vector_type(4)));

__device__ __forceinline__ unsigned short cvbf(float f){
  unsigned u = __float_as_uint(f);
  return (unsigned short)((u + 0x8000u) >> 16);
}

__device__ __forceinline__ void ldsload16(const void* gp, void* lp){
  __builtin_amdgcn_global_load_lds((const __attribute__((address_space(1))) void*)gp,
                                   (__attribute__((address_space(3))) void*)lp,
                                   16, 0, 0);
}

// ---------------- prep kernel: weight repack + dtype detect into d_ws ----------------
// ws[0..65536): W1T bf16, row n=g*64+h (256 x 256B), byte = n*256 + (k*2 ^ ((n&7)<<4))
// ws[65536..73728): W2T bf16, row t=g*16+p (64 x 128B); element slot e (=ks*32+q*8+j)
//   holds W2[g][h(e)][p], h(e) = (e&32)|((e&4)<<2)|((e>>1)&12)|(e&3)  (k-slot permutation
//   matching GEMM1's C^T fragment layout -> GEMM2 needs no hidden transpose), p>=4 zeros.
// ws[73728]: gshift (0=int32 gids, 1=int64) ; ws[73732]: mshift (0=byte mask, 2=int32 mask)
__global__ void prep_kernel(const float* __restrict__ W1, const float* __restrict__ W2,
                            const void* __restrict__ gids_raw, const void* __restrict__ mask_raw,
                            unsigned char* __restrict__ ws){
  int tid = threadIdx.x, bid = blockIdx.x;
  if (bid < 16){
    int chunk = bid*256 + tid;
    int n    = chunk >> 4;
    int kb16 = chunk & 15;
    int d0   = kb16 * 8;
    int g = n >> 6, h = n & 63;
    u16x8 v;
#pragma unroll
    for (int j=0;j<8;++j) v[j] = cvbf(W1[((g*DIM) + d0 + j)*64 + h]);
    unsigned off = (unsigned)n*256 + (((unsigned)kb16*16) ^ (((unsigned)(n&7))<<4));
    *(u16x8*)(ws + off) = v;
  } else {
#pragma unroll
    for (int i=0;i<16;++i){
      int el = tid + i*256;          // 0..4095 elements of W2T
      int t  = el >> 6;              // row t = g*16+p
      int e  = el & 63;              // k-slot within row
      int g = t >> 4, p = t & 15;
      int h = (e & 32) | ((e & 4) << 2) | ((e >> 1) & 12) | (e & 3);
      float f = (p < 4) ? W2[(g*64 + h)*4 + p] : 0.0f;
      unsigned off = 65536u + (unsigned)t*128 + (((unsigned)(e*2)) ^ (((unsigned)(t&7))<<4));
      *(unsigned short*)(ws + off) = cvbf(f);
    }
    if (tid < 64){
      const int* g32 = (const int*)gids_raw;
      int accg = 0;
#pragma unroll
      for (int i=0;i<8;++i) accg |= g32[(tid*8 + i)*2 + 1];
      const unsigned char* m8 = (const unsigned char*)mask_raw;
      int accm = 0;
#pragma unroll
      for (int i=0;i<16;++i){
        int off = tid*16 + i;
        if (off & 3) accm |= m8[off];
      }
      unsigned long long bg = __ballot(accg != 0);
      unsigned long long bm = __ballot(accm != 0);
      if (tid == 0){
        *(int*)(ws + 73728) = (bg == 0ull) ? 1 : 0;
        *(int*)(ws + 73732) = (bm == 0ull) ? 2 : 0;
      }
    }
  }
}

// ---------------- main kernel: 512-thread blocks, launch_bounds(512,2), nt=2 units ----------------
#define LDS_W2T 65536
#define LDS_B1  (65536+8192)
#define LDS_TOTAL (65536+8192+1024)

__global__ __launch_bounds__(512, 2)
void actor_kernel(const float* __restrict__ X, const int* __restrict__ gids,
                  const unsigned char* __restrict__ fmask,
                  const float* __restrict__ b1, const float* __restrict__ b2,
                  const unsigned char* __restrict__ ws, float* __restrict__ out){
  __shared__ char smem[LDS_TOTAL];
  const int tid  = threadIdx.x;
  const int wave = tid >> 6, lane = tid & 63;
  const int q    = lane >> 4, rS = lane & 15;
  const int swzA = (rS & 7) << 4;

  const int gshift = *(const int*)(ws + 73728);
  const int mshift = *(const int*)(ws + 73732);

  // --- stage W1T + W2T + b1 to LDS once per block (8 waves cooperate) ---
#pragma unroll
  for (int i=0;i<8;++i){
    int off = i*8192 + wave*1024;
    ldsload16(ws + off + lane*16, smem + off);
  }
  {
    int off = wave*1024;
    ldsload16(ws + 65536 + off + lane*16, smem + LDS_W2T + off);
  }
  if (wave == 0)
    ldsload16((const unsigned char*)b1 + lane*16, smem + LDS_B1);
  __syncthreads();   // weights resident

  const long base = (long)blockIdx.x * 512 + wave * 64;
  const f32x4 z = (f32x4){0.f,0.f,0.f,0.f};

#pragma unroll 1
  for (int u=0; u<2; ++u){
    const long row0 = base + u*32 + rS;   // nt=0 row; nt=1 is +16

    // --- loads for both 16-row halves ---
    int gb0, gb1;
    u32x4 mb0, mb1;
    f32x4 xb[2][4][2];
    {
      gb0 = gids[(size_t)row0 << gshift];
      gb1 = gids[(size_t)(row0 + 16) << gshift];
      if (mshift){
        mb0 = *(const u32x4*)(fmask + row0*16);
        mb1 = *(const u32x4*)(fmask + (row0+16)*16);
      } else {
        unsigned w0 = *(const unsigned*)(fmask + row0*4);
        unsigned w1 = *(const unsigned*)(fmask + (row0+16)*4);
        mb0[0]=w0&0xffu; mb0[1]=(w0>>8)&0xffu; mb0[2]=(w0>>16)&0xffu; mb0[3]=w0>>24;
        mb1[0]=w1&0xffu; mb1[1]=(w1>>8)&0xffu; mb1[2]=(w1>>16)&0xffu; mb1[3]=w1>>24;
      }
      const float* xp0 = X + row0 * DIM + q*8;
      const float* xp1 = X + (row0 + 16) * DIM + q*8;
#pragma unroll
      for (int k=0;k<4;++k){
        xb[0][k][0] = *(const f32x4*)(xp0 + k*32);
        xb[0][k][1] = *(const f32x4*)(xp0 + k*32 + 4);
        xb[1][k][0] = *(const f32x4*)(xp1 + k*32);
        xb[1][k][1] = *(const f32x4*)(xp1 + k*32 + 4);
      }
    }
    __builtin_amdgcn_sched_barrier(0);

    // --- convert to bf16 B-fragments (xb dies here) ---
    s16x8 bfr[2][4];
#pragma unroll
    for (int nt=0;nt<2;++nt)
#pragma unroll
      for (int k=0;k<4;++k){
        s16x8 v;
#pragma unroll
        for (int j=0;j<4;++j){ v[j] = (short)cvbf(xb[nt][k][0][j]); v[j+4] = (short)cvbf(xb[nt][k][1][j]); }
        bfr[nt][k] = v;
      }
    __builtin_amdgcn_sched_barrier(0);

    // --- fused GEMM1 -> +b1/relu -> GEMM2, per mt-pair; each LDS read feeds 2 MFMAs ---
    f32x4 acc2[4][2];
#pragma unroll
    for (int p=0;p<8;++p){
      f32x4 aA0, aA1, aB0, aB1;
#pragma unroll
      for (int k=0;k<4;++k){
        const s16x8 sA = *(const s16x8*)(smem + ((2*p  )*16 + rS)*256 + ((k*64 + q*16) ^ swzA));
        const s16x8 sB = *(const s16x8*)(smem + ((2*p+1)*16 + rS)*256 + ((k*64 + q*16) ^ swzA));
        aA0 = __builtin_amdgcn_mfma_f32_16x16x32_bf16(sA, bfr[0][k], (k==0)? z : aA0, 0,0,0);
        aA1 = __builtin_amdgcn_mfma_f32_16x16x32_bf16(sA, bfr[1][k], (k==0)? z : aA1, 0,0,0);
        aB0 = __builtin_amdgcn_mfma_f32_16x16x32_bf16(sB, bfr[0][k], (k==0)? z : aB0, 0,0,0);
        aB1 = __builtin_amdgcn_mfma_f32_16x16x32_bf16(sB, bfr[1][k], (k==0)? z : aB1, 0,0,0);
      }
      const f32x4 b1A = *(const f32x4*)(smem + LDS_B1 + (2*p  )*64 + q*16);
      const f32x4 b1B = *(const f32x4*)(smem + LDS_B1 + (2*p+1)*64 + q*16);
      const s16x8 af = *(const s16x8*)(smem + LDS_W2T + ((p>>1)*16 + rS)*128
                                       + (((p&1)*64 + q*16) ^ swzA));
      // nt = 0
      {
        f32x4 vA = aA0 + b1A;
        f32x4 vB = aB0 + b1B;
#pragma unroll
        for (int j=0;j<4;++j){
          vA[j] = vA[j] > 0.f ? vA[j] : 0.f;
          vB[j] = vB[j] > 0.f ? vB[j] : 0.f;
        }
        s16x8 hf;
#pragma unroll
        for (int j=0;j<4;++j){ hf[j] = (short)cvbf(vA[j]); hf[j+4] = (short)cvbf(vB[j]); }
        acc2[p>>1][0] = __builtin_amdgcn_mfma_f32_16x16x32_bf16(
            af, hf, (p&1) ? acc2[p>>1][0] : z, 0,0,0);
      }
      // nt = 1
      {
        f32x4 vA = aA1 + b1A;
        f32x4 vB = aB1 + b1B;
#pragma unroll
        for (int j=0;j<4;++j){
          vA[j] = vA[j] > 0.f ? vA[j] : 0.f;
          vB[j] = vB[j] > 0.f ? vB[j] : 0.f;
        }
        s16x8 hf;
#pragma unroll
        for (int j=0;j<4;++j){ hf[j] = (short)cvbf(vA[j]); hf[j+4] = (short)cvbf(vB[j]); }
        acc2[p>>1][1] = __builtin_amdgcn_mfma_f32_16x16x32_bf16(
            af, hf, (p&1) ? acc2[p>>1][1] : z, 0,0,0);
      }
      __builtin_amdgcn_sched_barrier(0);
    }

    // --- epilogues ---
#pragma unroll
    for (int nt=0;nt<2;++nt){
      int g = nt ? gb1 : gb0;
      u32x4 mb = nt ? mb1 : mb0;
      f32x4 lv = acc2[0][nt];
      lv = (g==1) ? acc2[1][nt] : lv;
      lv = (g==2) ? acc2[2][nt] : lv;
      lv = (g==3) ? acc2[3][nt] : lv;
      const f32x4 bs = *(const f32x4*)(b2 + g*4);
      f32x4 li;
#pragma unroll
      for (int p=0;p<4;++p)
        li[p] = mb[p] ? (lv[p] + bs[p]) : -1e9f;
      float m = fmaxf(fmaxf(li[0],li[1]), fmaxf(li[2],li[3]));
      f32x4 e;
#pragma unroll
      for (int p=0;p<4;++p) e[p] = __expf(li[p] - m);
      float inv = 1.0f / (e[0]+e[1]+e[2]+e[3]);
      f32x4 o;
#pragma unroll
      for (int p=0;p<4;++p) o[p] = e[p] * inv;
      if (q == 0)
        *(f32x4*)(out + (row0 + nt*16)*4) = o;
    }
  }
}

extern "C" void kernel_launch(void* const* d_in, const int* in_sizes, int n_in,
                              void* d_out, int out_size, void* d_ws, size_t ws_size,
                              hipStream_t stream){
  const float* X  = (const float*)d_in[0];
  const void*  gi = d_in[1];
  const void*  fm = d_in[2];
  const float* W1 = (const float*)d_in[3];
  const float* b1 = (const float*)d_in[4];
  const float* W2 = (const float*)d_in[5];
  const float* b2 = (const float*)d_in[6];
  unsigned char* ws = (unsigned char*)d_ws;
  float* out = (float*)d_out;

  prep_kernel<<<dim3(17), dim3(256), 0, stream>>>(W1, W2, gi, fm, ws);
  actor_kernel<<<dim3(512), dim3(512), 0, stream>>>(X, (const int*)gi,
                                                    (const unsigned char*)fm,
                                                    b1, b2, ws, out);
}

// Round 15
// 41.009 us; speedup vs baseline: 1.4191x; 1.1640x over previous
//
#include <hip/hip_runtime.h>
#include <hip/hip_bf16.h>
#include <cstdint>

#define NROWS 262144
#define DIM 128

typedef float f32x4 __attribute__((ext_vector_type(4)));
typedef short s16x8 __attribute__((ext_vector_type(8)));
typedef unsigned short u16x8 __attribute__((ext_vector_type(8)));
typedef unsigned int u32x4 __attribute__((ext_vector_type(4)));

__device__ __forceinline__ unsigned short cvbf(float f){
  unsigned u = __float_as_uint(f);
  return (unsigned short)((u + 0x8000u) >> 16);
}

__device__ __forceinline__ void ldsload16(const void* gp, void* lp){
  __builtin_amdgcn_global_load_lds((const __attribute__((address_space(1))) void*)gp,
                                   (__attribute__((address_space(3))) void*)lp,
                                   16, 0, 0);
}

// ---------------- prep kernel: weight repack + dtype detect into d_ws ----------------
// ws[0..65536): W1T bf16, row n=g*64+h (256 x 256B), byte = n*256 + (k*2 ^ ((n&7)<<4))
// ws[65536..73728): W2T bf16, row t=g*16+p (64 x 128B); element slot e (=ks*32+q*8+j)
//   holds W2[g][h(e)][p], h(e) = (e&32)|((e&4)<<2)|((e>>1)&12)|(e&3)  (k-slot permutation
//   matching GEMM1's C^T fragment layout -> GEMM2 needs no hidden transpose), p>=4 zeros.
// ws[73728]: gshift (0=int32 gids, 1=int64) ; ws[73732]: mshift (0=byte mask, 2=int32 mask)
__global__ void prep_kernel(const float* __restrict__ W1, const float* __restrict__ W2,
                            const void* __restrict__ gids_raw, const void* __restrict__ mask_raw,
                            unsigned char* __restrict__ ws){
  int tid = threadIdx.x, bid = blockIdx.x;
  if (bid < 16){
    int chunk = bid*256 + tid;
    int n    = chunk >> 4;
    int kb16 = chunk & 15;
    int d0   = kb16 * 8;
    int g = n >> 6, h = n & 63;
    u16x8 v;
#pragma unroll
    for (int j=0;j<8;++j) v[j] = cvbf(W1[((g*DIM) + d0 + j)*64 + h]);
    unsigned off = (unsigned)n*256 + (((unsigned)kb16*16) ^ (((unsigned)(n&7))<<4));
    *(u16x8*)(ws + off) = v;
  } else {
#pragma unroll
    for (int i=0;i<16;++i){
      int el = tid + i*256;          // 0..4095 elements of W2T
      int t  = el >> 6;              // row t = g*16+p
      int e  = el & 63;              // k-slot within row
      int g = t >> 4, p = t & 15;
      int h = (e & 32) | ((e & 4) << 2) | ((e >> 1) & 12) | (e & 3);
      float f = (p < 4) ? W2[(g*64 + h)*4 + p] : 0.0f;
      unsigned off = 65536u + (unsigned)t*128 + (((unsigned)(e*2)) ^ (((unsigned)(t&7))<<4));
      *(unsigned short*)(ws + off) = cvbf(f);
    }
    if (tid < 64){
      const int* g32 = (const int*)gids_raw;
      int accg = 0;
#pragma unroll
      for (int i=0;i<8;++i) accg |= g32[(tid*8 + i)*2 + 1];
      const unsigned char* m8 = (const unsigned char*)mask_raw;
      int accm = 0;
#pragma unroll
      for (int i=0;i<16;++i){
        int off = tid*16 + i;
        if (off & 3) accm |= m8[off];
      }
      unsigned long long bg = __ballot(accg != 0);
      unsigned long long bm = __ballot(accm != 0);
      if (tid == 0){
        *(int*)(ws + 73728) = (bg == 0ull) ? 1 : 0;
        *(int*)(ws + 73732) = (bm == 0ull) ? 2 : 0;
      }
    }
  }
}

// ---------------- main kernel: block-local group bucketing, per-group p-loop ----------------
#define LDS_W2T 65536
#define LDS_B1  (65536+8192)
#define PERM_OFF   (65536+8192+1024)        // short perm[640]
#define HIST_OFF   (PERM_OFF+1280)         // int hist[4]
#define CUR_OFF    (HIST_OFF+16)           // int cur[4]
#define NUNITS_OFF (CUR_OFF+16)            // int
#define UG_OFF     (NUNITS_OFF+16)         // int unit_g[20]
#define UP_OFF     (UG_OFF+80)             // int unit_pos[20]
#define LDS_TOTAL  (UP_OFF+80)

__global__ __launch_bounds__(256, 2)
void actor_kernel(const float* __restrict__ X, const int* __restrict__ gids,
                  const unsigned char* __restrict__ fmask,
                  const float* __restrict__ b1, const float* __restrict__ b2,
                  const unsigned char* __restrict__ ws, float* __restrict__ out){
  __shared__ char smem[LDS_TOTAL];
  const int tid  = threadIdx.x;
  const int wave = tid >> 6, lane = tid & 63;
  const int q    = lane >> 4, rS = lane & 15;
  const int swzA = (rS & 7) << 4;

  const int gshift = *(const int*)(ws + 73728);
  const int mshift = *(const int*)(ws + 73732);

  short* perm = (short*)(smem + PERM_OFF);
  int* hist = (int*)(smem + HIST_OFF);
  int* cur  = (int*)(smem + CUR_OFF);
  int* ug   = (int*)(smem + UG_OFF);
  int* up   = (int*)(smem + UP_OFF);

  // --- stage W1T + W2T + b1 to LDS (async) ---
#pragma unroll
  for (int i=0;i<16;++i){
    int off = i*4096 + wave*1024;
    ldsload16(ws + off + lane*16, smem + off);
  }
#pragma unroll
  for (int i=0;i<2;++i){
    int off = i*4096 + wave*1024;
    ldsload16(ws + 65536 + off + lane*16, smem + LDS_W2T + off);
  }
  if (wave == 0)
    ldsload16((const unsigned char*)b1 + lane*16, smem + LDS_B1);

  // --- block-local bucketing of 512 rows by group ---
  const long base = (long)blockIdx.x * 512;
  if (tid < 4) hist[tid] = 0;
#pragma unroll
  for (int i = 0; i < 3; ++i){
    int e = tid + i*256;
    if (e < 640) perm[e] = -1;
  }
  __syncthreads();
  const int g0 = gids[(size_t)(base + tid) << gshift] & 3;
  const int g1 = gids[(size_t)(base + 256 + tid) << gshift] & 3;
  atomicAdd(&hist[g0], 1);
  atomicAdd(&hist[g1], 1);
  __syncthreads();
  if (tid == 0){
    int s = 0, n = 0;
    for (int g=0; g<4; ++g){
      cur[g] = s;
      int padded = ((hist[g] + 31) >> 5) << 5;
      for (int k=0; k<padded; k+=32){ ug[n] = g; up[n] = s + k; ++n; }
      s += padded;
    }
    *(int*)(smem + NUNITS_OFF) = n;
  }
  __syncthreads();
  { int p0 = atomicAdd(&cur[g0], 1); perm[p0] = (short)tid;
    int p1 = atomicAdd(&cur[g1], 1); perm[p1] = (short)(256 + tid); }
  __syncthreads();   // also drains weight staging
  const int nunits = *(const int*)(smem + NUNITS_OFF);

  const f32x4 z = (f32x4){0.f,0.f,0.f,0.f};

#pragma unroll 1
  for (int uu = 0; uu < 5; ++uu){
    const int idx = wave + uu*4;
    if (idx >= nunits) break;
    const int g   = ug[idx];
    const int pos = up[idx];
    const int r0l = perm[pos + rS];
    const int r1l = perm[pos + 16 + rS];
    const long rr0 = base + (r0l < 0 ? 0 : r0l);
    const long rr1 = base + (r1l < 0 ? 0 : r1l);

    // --- masks ---
    u32x4 mb0, mb1;
    if (mshift){
      mb0 = *(const u32x4*)(fmask + rr0*16);
      mb1 = *(const u32x4*)(fmask + rr1*16);
    } else {
      unsigned w0 = *(const unsigned*)(fmask + rr0*4);
      unsigned w1 = *(const unsigned*)(fmask + rr1*4);
      mb0[0]=w0&0xffu; mb0[1]=(w0>>8)&0xffu; mb0[2]=(w0>>16)&0xffu; mb0[3]=w0>>24;
      mb1[0]=w1&0xffu; mb1[1]=(w1>>8)&0xffu; mb1[2]=(w1>>16)&0xffu; mb1[3]=w1>>24;
    }

    // --- X loads (gathered within block's 512-row window) ---
    f32x4 xb[2][4][2];
    {
      const float* xp0 = X + rr0 * DIM + q*8;
      const float* xp1 = X + rr1 * DIM + q*8;
#pragma unroll
      for (int k=0;k<4;++k){
        xb[0][k][0] = *(const f32x4*)(xp0 + k*32);
        xb[0][k][1] = *(const f32x4*)(xp0 + k*32 + 4);
        xb[1][k][0] = *(const f32x4*)(xp1 + k*32);
        xb[1][k][1] = *(const f32x4*)(xp1 + k*32 + 4);
      }
    }
    __builtin_amdgcn_sched_barrier(0);

    // --- cvt to bf16 B-fragments ---
    s16x8 bfr[2][4];
#pragma unroll
    for (int nt=0;nt<2;++nt)
#pragma unroll
      for (int k=0;k<4;++k){
        s16x8 v;
#pragma unroll
        for (int j=0;j<4;++j){ v[j] = (short)cvbf(xb[nt][k][0][j]); v[j+4] = (short)cvbf(xb[nt][k][1][j]); }
        bfr[nt][k] = v;
      }
    __builtin_amdgcn_sched_barrier(0);

    // --- fused GEMM1(group g only) -> +b1/relu -> GEMM2, pinned ---
    f32x4 acc2[2];
#pragma unroll
    for (int pp=0;pp<2;++pp){
      const int p = 2*g + pp;
      f32x4 aA0, aA1, aB0, aB1;
#pragma unroll
      for (int k=0;k<4;++k){
        const s16x8 sA = *(const s16x8*)(smem + ((2*p  )*16 + rS)*256 + ((k*64 + q*16) ^ swzA));
        const s16x8 sB = *(const s16x8*)(smem + ((2*p+1)*16 + rS)*256 + ((k*64 + q*16) ^ swzA));
        aA0 = __builtin_amdgcn_mfma_f32_16x16x32_bf16(sA, bfr[0][k], (k==0)? z : aA0, 0,0,0);
        aA1 = __builtin_amdgcn_mfma_f32_16x16x32_bf16(sA, bfr[1][k], (k==0)? z : aA1, 0,0,0);
        aB0 = __builtin_amdgcn_mfma_f32_16x16x32_bf16(sB, bfr[0][k], (k==0)? z : aB0, 0,0,0);
        aB1 = __builtin_amdgcn_mfma_f32_16x16x32_bf16(sB, bfr[1][k], (k==0)? z : aB1, 0,0,0);
      }
      const f32x4 b1A = *(const f32x4*)(smem + LDS_B1 + (2*p  )*64 + q*16);
      const f32x4 b1B = *(const f32x4*)(smem + LDS_B1 + (2*p+1)*64 + q*16);
      const s16x8 af = *(const s16x8*)(smem + LDS_W2T + (g*16 + rS)*128
                                       + ((pp*64 + q*16) ^ swzA));
      {
        f32x4 vA = aA0 + b1A, vB = aB0 + b1B;
#pragma unroll
        for (int j=0;j<4;++j){ vA[j] = vA[j] > 0.f ? vA[j] : 0.f; vB[j] = vB[j] > 0.f ? vB[j] : 0.f; }
        s16x8 hf;
#pragma unroll
        for (int j=0;j<4;++j){ hf[j] = (short)cvbf(vA[j]); hf[j+4] = (short)cvbf(vB[j]); }
        acc2[0] = __builtin_amdgcn_mfma_f32_16x16x32_bf16(af, hf, pp ? acc2[0] : z, 0,0,0);
      }
      {
        f32x4 vA = aA1 + b1A, vB = aB1 + b1B;
#pragma unroll
        for (int j=0;j<4;++j){ vA[j] = vA[j] > 0.f ? vA[j] : 0.f; vB[j] = vB[j] > 0.f ? vB[j] : 0.f; }
        s16x8 hf;
#pragma unroll
        for (int j=0;j<4;++j){ hf[j] = (short)cvbf(vA[j]); hf[j+4] = (short)cvbf(vB[j]); }
        acc2[1] = __builtin_amdgcn_mfma_f32_16x16x32_bf16(af, hf, pp ? acc2[1] : z, 0,0,0);
      }
      __builtin_amdgcn_sched_barrier(0);
    }

    // --- epilogues (group uniform: no select chain) ---
    const f32x4 bs = *(const f32x4*)(b2 + g*4);
#pragma unroll
    for (int nt=0;nt<2;++nt){
      u32x4 mb = nt ? mb1 : mb0;
      f32x4 lv = acc2[nt];
      f32x4 li;
#pragma unroll
      for (int p=0;p<4;++p)
        li[p] = mb[p] ? (lv[p] + bs[p]) : -1e9f;
      float m = fmaxf(fmaxf(li[0],li[1]), fmaxf(li[2],li[3]));
      f32x4 e;
#pragma unroll
      for (int p=0;p<4;++p) e[p] = __expf(li[p] - m);
      float inv = 1.0f / (e[0]+e[1]+e[2]+e[3]);
      f32x4 o;
#pragma unroll
      for (int p=0;p<4;++p) o[p] = e[p] * inv;
      int rl = nt ? r1l : r0l;
      long rr = nt ? rr1 : rr0;
      if (q == 0 && rl >= 0)
        *(f32x4*)(out + rr*4) = o;
    }
  }
}

extern "C" void kernel_launch(void* const* d_in, const int* in_sizes, int n_in,
                              void* d_out, int out_size, void* d_ws, size_t ws_size,
                              hipStream_t stream){
  const float* X  = (const float*)d_in[0];
  const void*  gi = d_in[1];
  const void*  fm = d_in[2];
  const float* W1 = (const float*)d_in[3];
  const float* b1 = (const float*)d_in[4];
  const float* W2 = (const float*)d_in[5];
  const float* b2 = (const float*)d_in[6];
  unsigned char* ws = (unsigned char*)d_ws;
  float* out = (float*)d_out;

  prep_kernel<<<dim3(17), dim3(256), 0, stream>>>(W1, W2, gi, fm, ws);
  actor_kernel<<<dim3(512), dim3(256), 0, stream>>>(X, (const int*)gi,
                                                    (const unsigned char*)fm,
                                                    b1, b2, ws, out);
}